// Round 4
// baseline (278.574 us; speedup 1.0000x reference)
//
#include <hip/hip_runtime.h>
#include <stdint.h>

#define NROWS 8192
#define HALF_N 4096
#define DIM 512
#define INV_TEMP 2.0f
#define E2SCALE 2.8853900817779268f  /* INV_TEMP * log2(e) */
#define LN2 0.6931471805599453f

typedef __bf16 bf16x8 __attribute__((ext_vector_type(8)));
typedef float f32x4 __attribute__((ext_vector_type(4)));

__device__ __forceinline__ unsigned f2bf(float f) {
  unsigned u = __float_as_uint(f);
  unsigned r = 0x7FFFu + ((u >> 16) & 1u);
  return (u + r) >> 16;  // round-to-nearest-even bf16 bits
}

// global -> LDS direct copy, 16B per lane; LDS dest is wave-uniform base + lane*16
__device__ __forceinline__ void gload_lds16(const unsigned short* g, unsigned short* l) {
  __builtin_amdgcn_global_load_lds(
      (const __attribute__((address_space(1))) unsigned int*)(uintptr_t)g,
      (__attribute__((address_space(3))) unsigned int*)(uint32_t)(uintptr_t)l,
      16, 0, 0);
}

// One wave per row: sumsq -> rsqrt -> bf16 store. Zeroes sumexp + completion counter.
__global__ void __launch_bounds__(256) k_normalize(const float* __restrict__ zi,
                                                   const float* __restrict__ zj,
                                                   unsigned short* __restrict__ zn,
                                                   float* __restrict__ sumexp,
                                                   int* __restrict__ counter) {
  int tid = threadIdx.x;
  int gid = blockIdx.x * 256 + tid;
  if (gid < NROWS) sumexp[gid] = 0.0f;
  if (gid == 0) *counter = 0;
  int wave = tid >> 6, lane = tid & 63;
  int row = blockIdx.x * 4 + wave;
  const float* src = (row < HALF_N) ? (zi + (size_t)row * DIM)
                                    : (zj + (size_t)(row - HALF_N) * DIM);
  const float4* s4 = (const float4*)src;
  float4 a = s4[lane];
  float4 b = s4[lane + 64];
  float ss = a.x * a.x + a.y * a.y + a.z * a.z + a.w * a.w +
             b.x * b.x + b.y * b.y + b.z * b.z + b.w * b.w;
#pragma unroll
  for (int off = 32; off > 0; off >>= 1) ss += __shfl_xor(ss, off, 64);
  float nrm = fmaxf(sqrtf(ss), 1e-8f);
  float inv = 1.0f / nrm;
  uint2 oa, ob;
  oa.x = f2bf(a.x * inv) | (f2bf(a.y * inv) << 16);
  oa.y = f2bf(a.z * inv) | (f2bf(a.w * inv) << 16);
  ob.x = f2bf(b.x * inv) | (f2bf(b.y * inv) << 16);
  ob.y = f2bf(b.z * inv) | (f2bf(b.w * inv) << 16);
  unsigned short* dst = zn + (size_t)row * DIM;
  *((uint2*)(dst + lane * 4)) = oa;
  *((uint2*)(dst + 256 + lane * 4)) = ob;
}

// Upper-triangular 128x128 tiles (sim symmetric): off-diag tiles feed row- AND col-sums.
// BK=64 double-buffered (64 KB LDS), 8-granule XOR swizzle (2-way = free).
// Last-finishing block computes the final loss (fused k_final).
__global__ void __launch_bounds__(256, 2) k_simsum(const unsigned short* __restrict__ zn,
                                                   float* __restrict__ sumexp,
                                                   float* __restrict__ posv,
                                                   int* __restrict__ counter,
                                                   float* __restrict__ out) {
  __shared__ __align__(16) unsigned short As[2][128 * 64];  // 2 x 16 KB
  __shared__ __align__(16) unsigned short Bs[2][128 * 64];  // 2 x 16 KB
  int tid = threadIdx.x;
  int wave = tid >> 6, lane = tid & 63;

  // triangular decode, tn-major: idx = tn(tn+1)/2 + tm, tm <= tn
  int idx = blockIdx.x;
  int tn = (int)((sqrtf(8.0f * idx + 1.0f) - 1.0f) * 0.5f);
  while (tn * (tn + 1) / 2 > idx) tn--;
  while ((tn + 1) * (tn + 2) / 2 <= idx) tn++;
  int tm = idx - tn * (tn + 1) / 2;
  int rowBase = tm * 128, colBase = tn * 128;
  int wr = (wave >> 1) * 64, wc = (wave & 1) * 64;  // wave's 64x64 quadrant
  int r15 = lane & 15, q = lane >> 4;

  // Staging (BK=64): rows of 128 B; 8 lanes cover one row; granule g of row r holds
  // global k-chunk g ^ (r & 7). Wave stages rows wave*32..+31 of A and B tiles.
  int rgrp = lane >> 3;                 // 0..7: row within 8-row instr group
  int xcol = (lane & 7) ^ rgrp;         // XOR-swizzled 16B-granule index
  const unsigned short* gA = zn + (size_t)(rowBase + wave * 32 + rgrp) * DIM + xcol * 8;
  const unsigned short* gB = zn + (size_t)(colBase + wave * 32 + rgrp) * DIM + xcol * 8;
  unsigned short* lA[2] = {&As[0][wave * 2048], &As[1][wave * 2048]};
  unsigned short* lB[2] = {&Bs[0][wave * 2048], &Bs[1][wave * 2048]};

#define STAGE(b)                                   \
  do {                                             \
    gload_lds16(gA, lA[b]);                        \
    gload_lds16(gA + 8 * DIM, lA[b] + 512);        \
    gload_lds16(gA + 16 * DIM, lA[b] + 1024);      \
    gload_lds16(gA + 24 * DIM, lA[b] + 1536);      \
    gload_lds16(gB, lB[b]);                        \
    gload_lds16(gB + 8 * DIM, lB[b] + 512);        \
    gload_lds16(gB + 16 * DIM, lB[b] + 1024);      \
    gload_lds16(gB + 24 * DIM, lB[b] + 1536);      \
    gA += 64; gB += 64;                            \
  } while (0)

  f32x4 acc[4][4];
#pragma unroll
  for (int i = 0; i < 4; i++)
#pragma unroll
    for (int j = 0; j < 4; j++) acc[i][j] = (f32x4){0.f, 0.f, 0.f, 0.f};

  int sw8 = r15 & 7;
  int aOff = (wr + r15) * 8;  // bf16x8 index of row wr+r15, granule 0
  int bOff = (wc + r15) * 8;

#define COMPUTE(b)                                                                   \
  do {                                                                               \
    const bf16x8* Av = (const bf16x8*)As[b];                                         \
    const bf16x8* Bv = (const bf16x8*)Bs[b];                                         \
    _Pragma("unroll") for (int t = 0; t < 2; t++) {                                  \
      int g = (t * 4 + q) ^ sw8;                                                     \
      bf16x8 af[4], bfr[4];                                                          \
      _Pragma("unroll") for (int i = 0; i < 4; i++) af[i] = Av[aOff + i * 128 + g];  \
      _Pragma("unroll") for (int j = 0; j < 4; j++) bfr[j] = Bv[bOff + j * 128 + g]; \
      _Pragma("unroll") for (int i = 0; i < 4; i++)                                  \
        _Pragma("unroll") for (int j = 0; j < 4; j++)                                \
          acc[i][j] = __builtin_amdgcn_mfma_f32_16x16x32_bf16(af[i], bfr[j],         \
                                                              acc[i][j], 0, 0, 0);   \
    }                                                                                \
  } while (0)

  STAGE(0);  // prologue: k-window 0
#pragma unroll
  for (int s = 0; s < 8; s += 2) {
    __syncthreads();           // drains window-s loads (in flight one full phase)
    if (s + 1 < 8) STAGE(1);   // issue window s+1 before computing s
    COMPUTE(0);
    __syncthreads();
    if (s + 2 < 8) STAGE(0);
    COMPUTE(1);
  }

  // ---- Epilogue. C/D layout: col = lane&15 (+j*16), row = q*4 + reg (+i*16). ----
  bool isDiag = (tm == tn);
  bool hasPos = (tn == tm + 32);
  int rsel = r15 & 3;
  bool diagLane = (wr == wc) && (q == (r15 >> 2));  // lane holding row==col elements

  if (isDiag && diagLane) {
#pragma unroll
    for (int i = 0; i < 4; i++) acc[i][i][rsel] = -1e30f;  // exp2 -> 0 (mask diagonal)
  }
  if (hasPos && diagLane) {
#pragma unroll
    for (int i = 0; i < 4; i++) {
      float s = acc[i][i][rsel] * INV_TEMP;
      int gr = rowBase + wr + i * 16 + r15;
      __hip_atomic_store(&posv[gr], s, __ATOMIC_RELAXED, __HIP_MEMORY_SCOPE_AGENT);
      __hip_atomic_store(&posv[gr + HALF_N], s, __ATOMIC_RELAXED, __HIP_MEMORY_SCOPE_AGENT);
    }
  }

  float rs[16], cs[4];
#pragma unroll
  for (int t = 0; t < 16; t++) rs[t] = 0.f;
#pragma unroll
  for (int t = 0; t < 4; t++) cs[t] = 0.f;
#pragma unroll
  for (int i = 0; i < 4; i++)
#pragma unroll
    for (int j = 0; j < 4; j++)
#pragma unroll
      for (int r = 0; r < 4; r++) {
        float e = __builtin_amdgcn_exp2f(acc[i][j][r] * E2SCALE);
        rs[i * 4 + r] += e;
        cs[j] += e;
      }

  // Fold-reduce rs[16] across the 16-lane r15 group; lane ends with row index r15.
#pragma unroll
  for (int t = 0; t < 8; t++) {
    float mine = (lane & 8) ? rs[t + 8] : rs[t];
    float oth = __shfl_xor((lane & 8) ? rs[t] : rs[t + 8], 8, 64);
    rs[t] = mine + oth;
  }
#pragma unroll
  for (int t = 0; t < 4; t++) {
    float mine = (lane & 4) ? rs[t + 4] : rs[t];
    float oth = __shfl_xor((lane & 4) ? rs[t] : rs[t + 4], 4, 64);
    rs[t] = mine + oth;
  }
#pragma unroll
  for (int t = 0; t < 2; t++) {
    float mine = (lane & 2) ? rs[t + 2] : rs[t];
    float oth = __shfl_xor((lane & 2) ? rs[t] : rs[t + 2], 2, 64);
    rs[t] = mine + oth;
  }
  {
    float mine = (lane & 1) ? rs[1] : rs[0];
    float oth = __shfl_xor((lane & 1) ? rs[0] : rs[1], 1, 64);
    rs[0] = mine + oth;
  }
  int myrow = rowBase + wr + ((r15 >> 2) * 16) + q * 4 + (r15 & 3);
  atomicAdd(&sumexp[myrow], rs[0]);

  if (!isDiag) {
#pragma unroll
    for (int t = 0; t < 2; t++) {
      float mine = (lane & 16) ? cs[t + 2] : cs[t];
      float oth = __shfl_xor((lane & 16) ? cs[t] : cs[t + 2], 16, 64);
      cs[t] = mine + oth;
    }
    {
      float mine = (lane & 32) ? cs[1] : cs[0];
      float oth = __shfl_xor((lane & 32) ? cs[0] : cs[1], 32, 64);
      cs[0] = mine + oth;
    }
    int myj = 2 * ((lane >> 4) & 1) + ((lane >> 5) & 1);
    atomicAdd(&sumexp[colBase + wc + myj * 16 + r15], cs[0]);
  }

  // ---- Fused finalization: last block to finish computes the loss. ----
  __threadfence();  // release our posv stores / atomics device-wide
  __shared__ int amLast;
  if (tid == 0) {
    int prev = __hip_atomic_fetch_add(counter, 1, __ATOMIC_ACQ_REL, __HIP_MEMORY_SCOPE_AGENT);
    amLast = (prev == (int)gridDim.x - 1);
  }
  __syncthreads();
  if (amLast) {
    __threadfence();  // acquire side
    float p = 0.f;
    for (int r = tid; r < NROWS; r += 256) {
      float se = __hip_atomic_load(&sumexp[r], __ATOMIC_RELAXED, __HIP_MEMORY_SCOPE_AGENT);
      float pv = __hip_atomic_load(&posv[r], __ATOMIC_RELAXED, __HIP_MEMORY_SCOPE_AGENT);
      p += __builtin_amdgcn_logf(se) * LN2 - pv;
    }
#pragma unroll
    for (int off = 32; off > 0; off >>= 1) p += __shfl_xor(p, off, 64);
    __shared__ float red[4];
    if (lane == 0) red[wave] = p;
    __syncthreads();
    if (tid == 0) out[0] = (red[0] + red[1] + red[2] + red[3]) / (float)NROWS;
  }
#undef STAGE
#undef COMPUTE
}

extern "C" void kernel_launch(void* const* d_in, const int* in_sizes, int n_in,
                              void* d_out, int out_size, void* d_ws, size_t ws_size,
                              hipStream_t stream) {
  const float* zi = (const float*)d_in[0];
  const float* zj = (const float*)d_in[1];
  unsigned short* zn = (unsigned short*)d_ws;                         // 8 MB
  float* sumexp = (float*)((char*)d_ws + (size_t)NROWS * DIM * 2);    // 32 KB
  float* posv = sumexp + NROWS;                                       // 32 KB
  int* counter = (int*)(posv + NROWS);                                // 4 B
  float* out = (float*)d_out;

  hipLaunchKernelGGL(k_normalize, dim3(2048), dim3(256), 0, stream, zi, zj, zn, sumexp, counter);
  hipLaunchKernelGGL(k_simsum, dim3(2080), dim3(256), 0, stream, zn, sumexp, posv, counter, out);
}